// Round 4
// baseline (497.055 us; speedup 1.0000x reference)
//
#include <hip/hip_runtime.h>
#include <stdint.h>

// BilinearScorer: out[n,r] = sum_{h,k} pred[n,h] U[h,r,k] args[n,k] + bias1[r,:].args[n,:] + bias2[r]
// n=4096, h=k=512, R=64.  137.4 GFLOP fp32-equivalent.
// R4 = R2 grid locality (r slowest: FETCH 68MB) + R3 round shape (BK=64: 32 MFMA
// per barrier drain) + launch_bounds(256,5) for 5 blocks/CU + faster prep.
// fp16 single-pass numerics (absmax 0.25, passes).

#define HID   512
#define ROLES 64
#define NTOK  4096
#define BM    128
#define BN    128
#define BK    64

typedef __attribute__((ext_vector_type(8))) _Float16 f16x8;  // MFMA A/B operand: 4 VGPRs
typedef __attribute__((ext_vector_type(4))) _Float16 f16x4;
typedef __attribute__((ext_vector_type(4))) float    f32x4;

__device__ __forceinline__ void async16(const void* g, void* l) {
  // global -> LDS direct copy, 16B/lane. LDS dest is wave-uniform base + lane*16;
  // per-lane SOURCE address is free (implements the store-side swizzle).
  __builtin_amdgcn_global_load_lds(
      (const __attribute__((address_space(1))) uint32_t*)g,
      (__attribute__((address_space(3))) uint32_t*)l, 16, 0, 0);
}

// ---- prep: pred fp32 -> fp16, fused out[n,r] = bias2[r] init ---------------
__global__ __launch_bounds__(256) void cvt_pred(const float* __restrict__ in,
                                                _Float16* __restrict__ outp,
                                                float* __restrict__ o,
                                                const float* __restrict__ b2) {
  const int idx = blockIdx.x * 256 + threadIdx.x;        // NTOK*HID/4 = 524288 threads
  const float4 v = ((const float4*)in)[idx];
  f16x4 t;
  t[0] = (_Float16)v.x; t[1] = (_Float16)v.y;
  t[2] = (_Float16)v.z; t[3] = (_Float16)v.w;
  ((f16x4*)outp)[idx] = t;
  if (idx < NTOK * ROLES) o[idx] = b2[idx & (ROLES - 1)];  // 262144 < 524288
}

// ---- prep: U[h][r][k] -> Ut[r][k][h] fp16, 128x128 fp32 LDS tile ----------
__global__ __launch_bounds__(256) void cvt_u(const float* __restrict__ U,
                                             _Float16* __restrict__ ut) {
  __shared__ float tile[128][129];               // stride 129 words: col reads conflict-free
  const int h0 = blockIdx.x * 128, k0 = blockIdx.y * 128, r = blockIdx.z;
  const int t = threadIdx.x;
  // read: 16 passes x 8 rows; 512B contiguous per row
  const int rr = t >> 5, c4 = (t & 31) * 4;
#pragma unroll
  for (int pass = 0; pass < 16; pass++) {
    const int row = pass * 8 + rr;
    const float4 v = *(const float4*)(U + ((size_t)(h0 + row) * ROLES + r) * HID + k0 + c4);
    tile[row][c4 + 0] = v.x; tile[row][c4 + 1] = v.y;
    tile[row][c4 + 2] = v.z; tile[row][c4 + 3] = v.w;
  }
  __syncthreads();
  // write: 8 passes x 16 k-rows; 256B contiguous per k-row
  const int kr = t >> 4, hc = (t & 15) * 8;
#pragma unroll
  for (int pass = 0; pass < 8; pass++) {
    const int k = pass * 16 + kr;
    alignas(16) _Float16 hb[8];
#pragma unroll
    for (int j = 0; j < 8; j++) hb[j] = (_Float16)tile[hc + j][k];
    *(uint4*)(ut + ((size_t)r * HID + k0 + k) * HID + h0 + hc) = *(const uint4*)hb;
  }
}

// ---- main fused GEMM ------------------------------------------------------
__global__ __launch_bounds__(256, 5) void bilinear_mfma(
    const _Float16* __restrict__ predf, const _Float16* __restrict__ utf,
    const float* __restrict__ args, const float* __restrict__ bias1,
    float* __restrict__ out) {
  __shared__ _Float16 sA[BM * BK];               // 16 KB
  __shared__ _Float16 sB[BN * BK];               // 16 KB

  const int nblk = blockIdx.x, mblk = blockIdx.y, r = blockIdx.z;
  const int m0 = mblk * BM, n0 = nblk * BN;
  const int tid  = threadIdx.x;
  const int wave = tid >> 6, lane = tid & 63;
  const int col  = lane & 15, quad = lane >> 4;
  const int wm = (wave & 1) * 64, wn = (wave >> 1) * 64;

  // staging: tile = 128 rows x 64 f16 (128B/row) = 1024 x 16B chunks, 4 calls.
  // XOR swizzle: LDS slot s of row i holds global chunk (s ^ (i&7)); every 8
  // consecutive lanes cover all 8 bank groups (R3-verified: 0 conflicts).
  const int i_loc = tid >> 3;                    // row 0..31 within call (+32/call)
  const int ko    = ((tid & 7) ^ (i_loc & 7)) * 8;
  const size_t offA = (size_t)(m0 + i_loc) * HID + ko;
  const size_t offB = ((size_t)r * HID + n0 + i_loc) * HID + ko;
  const int ldsW = wave * 512;                   // f16 elems (64 chunks/wave/call)

  // reader slots: row&7 == col&7 for all frag rows (wm, 16*mt ≡ 0 mod 8)
  const int slotL8 = (quad ^ (col & 7)) * 8;     // k-chunks 0..3  (k in [0,32))
  const int slotH8 = slotL8 ^ 32;                // k-chunks 4..7  (k in [32,64))
  int rowA[4], rowB[4];
#pragma unroll
  for (int mt = 0; mt < 4; mt++) rowA[mt] = (wm + mt * 16 + col) * BK;
#pragma unroll
  for (int nt = 0; nt < 4; nt++) rowB[nt] = (wn + nt * 16 + col) * BK;

  f32x4 acc[4][4];
#pragma unroll
  for (int a = 0; a < 4; a++)
#pragma unroll
    for (int b = 0; b < 4; b++) acc[a][b] = (f32x4){0.f, 0.f, 0.f, 0.f};

  for (int k0 = 0; k0 < HID; k0 += BK) {
#pragma unroll
    for (int c = 0; c < 4; c++) {
      async16(predf + offA + (size_t)(c * 32) * HID + k0, sA + c * 2048 + ldsW);
      async16(utf   + offB + (size_t)(c * 32) * HID + k0, sB + c * 2048 + ldsW);
    }
    __syncthreads();                             // drains vmcnt (staging done)

    {                                            // phase 0: k in [k0, k0+32)
      f16x8 a[4], b[4];
#pragma unroll
      for (int mt = 0; mt < 4; mt++) a[mt] = *(const f16x8*)(sA + rowA[mt] + slotL8);
#pragma unroll
      for (int nt = 0; nt < 4; nt++) b[nt] = *(const f16x8*)(sB + rowB[nt] + slotL8);
#pragma unroll
      for (int mt = 0; mt < 4; mt++)
#pragma unroll
        for (int nt = 0; nt < 4; nt++)
          acc[mt][nt] = __builtin_amdgcn_mfma_f32_16x16x32_f16(a[mt], b[nt], acc[mt][nt], 0, 0, 0);
    }
    {                                            // phase 1: k in [k0+32, k0+64)
      f16x8 a[4], b[4];
#pragma unroll
      for (int mt = 0; mt < 4; mt++) a[mt] = *(const f16x8*)(sA + rowA[mt] + slotH8);
#pragma unroll
      for (int nt = 0; nt < 4; nt++) b[nt] = *(const f16x8*)(sB + rowB[nt] + slotH8);
#pragma unroll
      for (int mt = 0; mt < 4; mt++)
#pragma unroll
        for (int nt = 0; nt < 4; nt++)
          acc[mt][nt] = __builtin_amdgcn_mfma_f32_16x16x32_f16(a[mt], b[nt], acc[mt][nt], 0, 0, 0);
    }
    __syncthreads();
  }

  // epilogue: partial[m] = sum_n (T[m,n] + bias1[r,n]) * args[m,n], atomic into out
  float b1v[4];
#pragma unroll
  for (int nt = 0; nt < 4; nt++)
    b1v[nt] = bias1[r * HID + n0 + wn + nt * 16 + col];

#pragma unroll
  for (int mt = 0; mt < 4; mt++) {
#pragma unroll
    for (int reg = 0; reg < 4; reg++) {
      const int m = m0 + wm + mt * 16 + quad * 4 + reg;   // C/D row = quad*4+reg (m89)
      const float* arow = args + (size_t)m * HID + n0 + wn + col;
      float s = 0.f;
#pragma unroll
      for (int nt = 0; nt < 4; nt++)
        s += (acc[mt][nt][reg] + b1v[nt]) * arow[nt * 16];
      s += __shfl_xor(s, 1);
      s += __shfl_xor(s, 2);
      s += __shfl_xor(s, 4);
      s += __shfl_xor(s, 8);                     // reduce 16-lane col group
      if (col == 0) atomicAdd(out + (size_t)m * ROLES + r, s);
    }
  }
}

// ---- correctness fallback if workspace is too small (slow, pure fp32) -----
__global__ __launch_bounds__(256) void fallback_k(
    const float* __restrict__ pred, const float* __restrict__ args,
    const float* __restrict__ U, const float* __restrict__ b1,
    const float* __restrict__ b2, float* __restrict__ out) {
  const int idx = blockIdx.x * 256 + threadIdx.x;   // 262144
  const int r = idx >> 12;                          // block-uniform role
  const int n = idx & (NTOK - 1);
  const float* arow = args + (size_t)n * HID;
  const float* prow = pred + (size_t)n * HID;
  float acc = 0.f;
  for (int h = 0; h < HID; h++) {
    const float* urow = U + ((size_t)h * ROLES + r) * HID;
    float s = 0.f;
    for (int k = 0; k < HID; k++) s = fmaf(urow[k], arow[k], s);
    acc = fmaf(prow[h], s, acc);
  }
  float sb = 0.f;
  const float* brow = b1 + (size_t)r * HID;
  for (int k = 0; k < HID; k++) sb = fmaf(brow[k], arow[k], sb);
  out[(size_t)n * ROLES + r] = acc + sb + b2[r];
}

extern "C" void kernel_launch(void* const* d_in, const int* in_sizes, int n_in,
                              void* d_out, int out_size, void* d_ws, size_t ws_size,
                              hipStream_t stream) {
  const float* pred = (const float*)d_in[0];
  const float* args = (const float*)d_in[1];
  const float* U    = (const float*)d_in[2];
  const float* b1   = (const float*)d_in[3];
  const float* b2   = (const float*)d_in[4];
  float* out = (float*)d_out;

  const size_t PRED_ELEMS = (size_t)NTOK * HID;         // 2,097,152
  const size_t U_ELEMS    = (size_t)HID * ROLES * HID;  // 16,777,216
  const size_t WS_NEEDED  = (PRED_ELEMS + U_ELEMS) * sizeof(_Float16); // ~36 MiB

  if (ws_size < WS_NEEDED) {
    hipLaunchKernelGGL(fallback_k, dim3((NTOK * ROLES) / 256), dim3(256), 0, stream,
                       pred, args, U, b1, b2, out);
    return;
  }

  _Float16* predf = (_Float16*)d_ws;
  _Float16* utf   = predf + PRED_ELEMS;

  hipLaunchKernelGGL(cvt_pred, dim3((unsigned)(PRED_ELEMS / 4 / 256)), dim3(256), 0, stream,
                     pred, predf, out, b2);
  hipLaunchKernelGGL(cvt_u, dim3(HID / 128, HID / 128, ROLES), dim3(256), 0, stream,
                     U, utf);
  hipLaunchKernelGGL(bilinear_mfma, dim3(HID / BN, NTOK / BM, ROLES), dim3(256), 0, stream,
                     predf, utf, args, b1, out);
}

// Round 5
// 341.219 us; speedup vs baseline: 1.4567x; 1.4567x over previous
//
#include <hip/hip_runtime.h>
#include <stdint.h>

// BilinearScorer: out[n,r] = sum_{h,k} pred[n,h] U[h,r,k] args[n,k] + bias1[r,:].args[n,:] + bias2[r]
// n=4096, h=k=512, R=64.  137.4 GFLOP fp32-equivalent.
// R5 = R4 with __launch_bounds__(256,3).
// R4 post-mortem: (256,5) capped the UNIFIED VGPR+AGPR budget at ~102 < the ~148-reg
// footprint (84 VGPR + 64 AGPR acc) -> accumulator spill to scratch (WRITE_SIZE 690MB,
// VGPR_Count 48, MfmaUtil 14%). (256,3) caps at ~170: fits, 3 blocks/CU — the natural
// occupancy for this footprint.  Grid keeps R2-verified locality (r slowest, FETCH 68MB);
// BK=64 keeps 32 MFMA per barrier drain.  fp16 single-pass numerics (absmax 0.25 passes).

#define HID   512
#define ROLES 64
#define NTOK  4096
#define BM    128
#define BN    128
#define BK    64

typedef __attribute__((ext_vector_type(8))) _Float16 f16x8;  // MFMA A/B operand: 4 VGPRs
typedef __attribute__((ext_vector_type(4))) _Float16 f16x4;
typedef __attribute__((ext_vector_type(4))) float    f32x4;

__device__ __forceinline__ void async16(const void* g, void* l) {
  // global -> LDS direct copy, 16B/lane. LDS dest is wave-uniform base + lane*16;
  // per-lane SOURCE address is free (implements the store-side swizzle).
  __builtin_amdgcn_global_load_lds(
      (const __attribute__((address_space(1))) uint32_t*)g,
      (__attribute__((address_space(3))) uint32_t*)l, 16, 0, 0);
}

// ---- prep: pred fp32 -> fp16, fused out[n,r] = bias2[r] init ---------------
__global__ __launch_bounds__(256) void cvt_pred(const float* __restrict__ in,
                                                _Float16* __restrict__ outp,
                                                float* __restrict__ o,
                                                const float* __restrict__ b2) {
  const int idx = blockIdx.x * 256 + threadIdx.x;        // NTOK*HID/4 = 524288 threads
  const float4 v = ((const float4*)in)[idx];
  f16x4 t;
  t[0] = (_Float16)v.x; t[1] = (_Float16)v.y;
  t[2] = (_Float16)v.z; t[3] = (_Float16)v.w;
  ((f16x4*)outp)[idx] = t;
  if (idx < NTOK * ROLES) o[idx] = b2[idx & (ROLES - 1)];  // 262144 < 524288
}

// ---- prep: U[h][r][k] -> Ut[r][k][h] fp16, 128x128 fp32 LDS tile ----------
__global__ __launch_bounds__(256) void cvt_u(const float* __restrict__ U,
                                             _Float16* __restrict__ ut) {
  __shared__ float tile[128][129];               // stride 129 words: col reads conflict-free
  const int h0 = blockIdx.x * 128, k0 = blockIdx.y * 128, r = blockIdx.z;
  const int t = threadIdx.x;
  // read: 16 passes x 8 rows; 512B contiguous per row
  const int rr = t >> 5, c4 = (t & 31) * 4;
#pragma unroll
  for (int pass = 0; pass < 16; pass++) {
    const int row = pass * 8 + rr;
    const float4 v = *(const float4*)(U + ((size_t)(h0 + row) * ROLES + r) * HID + k0 + c4);
    tile[row][c4 + 0] = v.x; tile[row][c4 + 1] = v.y;
    tile[row][c4 + 2] = v.z; tile[row][c4 + 3] = v.w;
  }
  __syncthreads();
  // write: 8 passes x 16 k-rows; 256B contiguous per k-row
  const int kr = t >> 4, hc = (t & 15) * 8;
#pragma unroll
  for (int pass = 0; pass < 8; pass++) {
    const int k = pass * 16 + kr;
    alignas(16) _Float16 hb[8];
#pragma unroll
    for (int j = 0; j < 8; j++) hb[j] = (_Float16)tile[hc + j][k];
    *(uint4*)(ut + ((size_t)r * HID + k0 + k) * HID + h0 + hc) = *(const uint4*)hb;
  }
}

// ---- main fused GEMM ------------------------------------------------------
__global__ __launch_bounds__(256, 3) void bilinear_mfma(
    const _Float16* __restrict__ predf, const _Float16* __restrict__ utf,
    const float* __restrict__ args, const float* __restrict__ bias1,
    float* __restrict__ out) {
  __shared__ _Float16 sA[BM * BK];               // 16 KB
  __shared__ _Float16 sB[BN * BK];               // 16 KB

  const int nblk = blockIdx.x, mblk = blockIdx.y, r = blockIdx.z;
  const int m0 = mblk * BM, n0 = nblk * BN;
  const int tid  = threadIdx.x;
  const int wave = tid >> 6, lane = tid & 63;
  const int col  = lane & 15, quad = lane >> 4;
  const int wm = (wave & 1) * 64, wn = (wave >> 1) * 64;

  // staging: tile = 128 rows x 64 f16 (128B/row) = 1024 x 16B chunks, 4 calls.
  // XOR swizzle: LDS slot s of row i holds global chunk (s ^ (i&7)); every 8
  // consecutive lanes cover all 8 bank groups (R2/R3-verified: 0 conflicts).
  const int i_loc = tid >> 3;                    // row 0..31 within call (+32/call)
  const int ko    = ((tid & 7) ^ (i_loc & 7)) * 8;
  const size_t offA = (size_t)(m0 + i_loc) * HID + ko;
  const size_t offB = ((size_t)r * HID + n0 + i_loc) * HID + ko;
  const int ldsW = wave * 512;                   // f16 elems (64 chunks/wave/call)

  // reader slots: row&7 == col&7 for all frag rows (wm, 16*mt ≡ 0 mod 8)
  const int slotL8 = (quad ^ (col & 7)) * 8;     // k-chunks 0..3  (k in [0,32))
  const int slotH8 = slotL8 ^ 32;                // k-chunks 4..7  (k in [32,64))
  int rowA[4], rowB[4];
#pragma unroll
  for (int mt = 0; mt < 4; mt++) rowA[mt] = (wm + mt * 16 + col) * BK;
#pragma unroll
  for (int nt = 0; nt < 4; nt++) rowB[nt] = (wn + nt * 16 + col) * BK;

  f32x4 acc[4][4];
#pragma unroll
  for (int a = 0; a < 4; a++)
#pragma unroll
    for (int b = 0; b < 4; b++) acc[a][b] = (f32x4){0.f, 0.f, 0.f, 0.f};

  for (int k0 = 0; k0 < HID; k0 += BK) {
#pragma unroll
    for (int c = 0; c < 4; c++) {
      async16(predf + offA + (size_t)(c * 32) * HID + k0, sA + c * 2048 + ldsW);
      async16(utf   + offB + (size_t)(c * 32) * HID + k0, sB + c * 2048 + ldsW);
    }
    __syncthreads();                             // drains vmcnt (staging done)

    {                                            // phase 0: k in [k0, k0+32)
      f16x8 a[4], b[4];
#pragma unroll
      for (int mt = 0; mt < 4; mt++) a[mt] = *(const f16x8*)(sA + rowA[mt] + slotL8);
#pragma unroll
      for (int nt = 0; nt < 4; nt++) b[nt] = *(const f16x8*)(sB + rowB[nt] + slotL8);
#pragma unroll
      for (int mt = 0; mt < 4; mt++)
#pragma unroll
        for (int nt = 0; nt < 4; nt++)
          acc[mt][nt] = __builtin_amdgcn_mfma_f32_16x16x32_f16(a[mt], b[nt], acc[mt][nt], 0, 0, 0);
    }
    {                                            // phase 1: k in [k0+32, k0+64)
      f16x8 a[4], b[4];
#pragma unroll
      for (int mt = 0; mt < 4; mt++) a[mt] = *(const f16x8*)(sA + rowA[mt] + slotH8);
#pragma unroll
      for (int nt = 0; nt < 4; nt++) b[nt] = *(const f16x8*)(sB + rowB[nt] + slotH8);
#pragma unroll
      for (int mt = 0; mt < 4; mt++)
#pragma unroll
        for (int nt = 0; nt < 4; nt++)
          acc[mt][nt] = __builtin_amdgcn_mfma_f32_16x16x32_f16(a[mt], b[nt], acc[mt][nt], 0, 0, 0);
    }
    __syncthreads();
  }

  // epilogue: partial[m] = sum_n (T[m,n] + bias1[r,n]) * args[m,n], atomic into out
  float b1v[4];
#pragma unroll
  for (int nt = 0; nt < 4; nt++)
    b1v[nt] = bias1[r * HID + n0 + wn + nt * 16 + col];

#pragma unroll
  for (int mt = 0; mt < 4; mt++) {
#pragma unroll
    for (int reg = 0; reg < 4; reg++) {
      const int m = m0 + wm + mt * 16 + quad * 4 + reg;   // C/D row = quad*4+reg (m89)
      const float* arow = args + (size_t)m * HID + n0 + wn + col;
      float s = 0.f;
#pragma unroll
      for (int nt = 0; nt < 4; nt++)
        s += (acc[mt][nt][reg] + b1v[nt]) * arow[nt * 16];
      s += __shfl_xor(s, 1);
      s += __shfl_xor(s, 2);
      s += __shfl_xor(s, 4);
      s += __shfl_xor(s, 8);                     // reduce 16-lane col group
      if (col == 0) atomicAdd(out + (size_t)m * ROLES + r, s);
    }
  }
}

// ---- correctness fallback if workspace is too small (slow, pure fp32) -----
__global__ __launch_bounds__(256) void fallback_k(
    const float* __restrict__ pred, const float* __restrict__ args,
    const float* __restrict__ U, const float* __restrict__ b1,
    const float* __restrict__ b2, float* __restrict__ out) {
  const int idx = blockIdx.x * 256 + threadIdx.x;   // 262144
  const int r = idx >> 12;                          // block-uniform role
  const int n = idx & (NTOK - 1);
  const float* arow = args + (size_t)n * HID;
  const float* prow = pred + (size_t)n * HID;
  float acc = 0.f;
  for (int h = 0; h < HID; h++) {
    const float* urow = U + ((size_t)h * ROLES + r) * HID;
    float s = 0.f;
    for (int k = 0; k < HID; k++) s = fmaf(urow[k], arow[k], s);
    acc = fmaf(prow[h], s, acc);
  }
  float sb = 0.f;
  const float* brow = b1 + (size_t)r * HID;
  for (int k = 0; k < HID; k++) sb = fmaf(brow[k], arow[k], sb);
  out[(size_t)n * ROLES + r] = acc + sb + b2[r];
}

extern "C" void kernel_launch(void* const* d_in, const int* in_sizes, int n_in,
                              void* d_out, int out_size, void* d_ws, size_t ws_size,
                              hipStream_t stream) {
  const float* pred = (const float*)d_in[0];
  const float* args = (const float*)d_in[1];
  const float* U    = (const float*)d_in[2];
  const float* b1   = (const float*)d_in[3];
  const float* b2   = (const float*)d_in[4];
  float* out = (float*)d_out;

  const size_t PRED_ELEMS = (size_t)NTOK * HID;         // 2,097,152
  const size_t U_ELEMS    = (size_t)HID * ROLES * HID;  // 16,777,216
  const size_t WS_NEEDED  = (PRED_ELEMS + U_ELEMS) * sizeof(_Float16); // ~36 MiB

  if (ws_size < WS_NEEDED) {
    hipLaunchKernelGGL(fallback_k, dim3((NTOK * ROLES) / 256), dim3(256), 0, stream,
                       pred, args, U, b1, b2, out);
    return;
  }

  _Float16* predf = (_Float16*)d_ws;
  _Float16* utf   = predf + PRED_ELEMS;

  hipLaunchKernelGGL(cvt_pred, dim3((unsigned)(PRED_ELEMS / 4 / 256)), dim3(256), 0, stream,
                     pred, predf, out, b2);
  hipLaunchKernelGGL(cvt_u, dim3(HID / 128, HID / 128, ROLES), dim3(256), 0, stream,
                     U, utf);
  hipLaunchKernelGGL(bilinear_mfma, dim3(HID / BN, NTOK / BM, ROLES), dim3(256), 0, stream,
                     predf, utf, args, b1, out);
}